// Round 6
// baseline (5785.728 us; speedup 1.0000x reference)
//
#include <hip/hip_runtime.h>
#include <hip/hip_bf16.h>
#include <math.h>

// ---------------- problem constants ----------------
#define T_    512
#define B_    256
#define INP_  128
#define HID_  256
#define OUT_  64
#define DT_   0.1f
#define CPL_  0.1f

typedef __attribute__((ext_vector_type(8))) short          bf16x8;
typedef __attribute__((ext_vector_type(4))) float          f32x4;
typedef __attribute__((ext_vector_type(4))) unsigned short u16x4;

// ---------------- ws layout (ushort units, FRAGMENT-PERMUTED) ----------------
// H region: 7 matrices (WH,WTAUH,WZR,WZI,WTAUZ,H2Z*CPL,Z2H*CPL), each 256x256.
//   ws[g*65536 + T*4096 + kt*512 + l*8 + j] = W_g[T*16 + (l&15)][kt*32 + (l>>4)*8 + j]
// U region: 2 matrices (UH, UZ), each 256x128, tile stride 2048.
// OUT region: 2 matrices (OH, OZ), each 64x256, tile stride 4096.
#define G_WH    0
#define G_WTAUH 1
#define G_WZR   2
#define G_WZI   3
#define G_WTAUZ 4
#define G_H2Z   5
#define G_Z2H   6
#define UH     458752   // 7*65536
#define UZ     491520
#define OH     524288
#define OZ     540672
#define NW_TOTAL 557056
#define BIAS_OFF_BYTES (NW_TOTAL * 2)
// bias arrays (float offsets within bias region)
#define BT_H    0
#define BTAU_H  256
#define BH_TOT  512
#define BT_ZR   768
#define BT_ZI   1024
#define BTAU_Z  1280
#define BZR_TOT 1536
#define BZI_TOT 1792
#define BY      2048   // 64 floats
#define CTR_OFF_BYTES   (BIAS_OFF_BYTES + 8448)   // 16 counters, 64B apart
#define STATE_OFF_BYTES (CTR_OFF_BYTES + 1024)
// state image: [parity2][rg16][32768 B] -- exact byte-image of sst (4 states x 8192B,
// XOR-swizzled). Publishers scatter u32 col-pairs; readers passthrough to LDS.

// fp32 -> bf16, round-to-nearest-even
__device__ __forceinline__ unsigned short f2bf(float f) {
    unsigned int u = __float_as_uint(f);
    u += 0x7fffu + ((u >> 16) & 1u);
    return (unsigned short)(u >> 16);
}

__device__ __forceinline__ float rcp_(float x) { return __builtin_amdgcn_rcpf(x); }
__device__ __forceinline__ float sigmoid_fast(float x) {
    return rcp_(1.0f + __expf(-x));
}
__device__ __forceinline__ float tanh_fast(float x) {
    return 1.0f - 2.0f * rcp_(__expf(2.0f * x) + 1.0f);
}

// ---------------- prep: weights fp32 -> bf16, fragment-permuted ----------------
__global__ void prep_weights(const float* __restrict__ Wh,   const float* __restrict__ Wtauh,
                             const float* __restrict__ Wzr,  const float* __restrict__ Wzi,
                             const float* __restrict__ Wtauz,const float* __restrict__ h2z,
                             const float* __restrict__ z2h,  const float* __restrict__ Uh,
                             const float* __restrict__ Uz,   const float* __restrict__ oh,
                             const float* __restrict__ oz,   unsigned short* __restrict__ ws) {
    int fid = blockIdx.x * 256 + threadIdx.x;   // one 8-elem fragment per thread
    if (fid >= NW_TOTAL / 8) return;
    int o = fid * 8;
    const float* src;
    int row, col, K;
    float scale = 1.0f;
    if (o < UH) {                       // H region, K=256
        int g  = o >> 16;
        int r  = o & 65535;
        int T  = r >> 12;
        int r2 = r & 4095;
        int kt = r2 >> 9;
        int l  = (r2 & 511) >> 3;
        row = T * 16 + (l & 15);
        col = kt * 32 + (l >> 4) * 8;
        K = 256;
        if      (g == G_WH)    src = Wh;
        else if (g == G_WTAUH) src = Wtauh;
        else if (g == G_WZR)   src = Wzr;
        else if (g == G_WZI)   src = Wzi;
        else if (g == G_WTAUZ) src = Wtauz;
        else if (g == G_H2Z)   { src = h2z; scale = CPL_; }
        else                   { src = z2h; scale = CPL_; }
    } else if (o < OH) {                // U region, K=128
        int g  = (o - UH) >> 15;
        int r  = (o - UH) & 32767;
        int T  = r >> 11;
        int r2 = r & 2047;
        int kt = r2 >> 9;
        int l  = (r2 & 511) >> 3;
        row = T * 16 + (l & 15);
        col = kt * 32 + (l >> 4) * 8;
        K = 128;
        src = g ? Uz : Uh;
    } else {                            // OUT region, K=256
        int g  = (o - OH) >> 14;
        int r  = (o - OH) & 16383;
        int T  = r >> 12;
        int r2 = r & 4095;
        int kt = r2 >> 9;
        int l  = (r2 & 511) >> 3;
        row = T * 16 + (l & 15);
        col = kt * 32 + (l >> 4) * 8;
        K = 256;
        src = g ? oz : oh;
    }
    const float* p = src + (size_t)row * K + col;
    float4 v0 = *(const float4*)p;
    float4 v1 = *(const float4*)(p + 4);
    u16x4 a, b;
    a.x = f2bf(v0.x * scale); a.y = f2bf(v0.y * scale);
    a.z = f2bf(v0.z * scale); a.w = f2bf(v0.w * scale);
    b.x = f2bf(v1.x * scale); b.y = f2bf(v1.y * scale);
    b.z = f2bf(v1.z * scale); b.w = f2bf(v1.w * scale);
    *(u16x4*)(ws + o)     = a;
    *(u16x4*)(ws + o + 4) = b;
}

// ---------------- prep: folded biases (fp32) + zero barrier counters ----------------
__global__ void prep_bias(const float* __restrict__ Whb,  const float* __restrict__ Wtauhb,
                          const float* __restrict__ Uhb,  const float* __restrict__ bh,
                          const float* __restrict__ z2hb, const float* __restrict__ Wzrb,
                          const float* __restrict__ Wzib, const float* __restrict__ Wtauzb,
                          const float* __restrict__ Uzb,  const float* __restrict__ bzr,
                          const float* __restrict__ bzi,  const float* __restrict__ h2zb,
                          const float* __restrict__ ohb,  const float* __restrict__ ozb,
                          float* __restrict__ bias) {
    int n = threadIdx.x;
    if (n < 256) {
        bias[BT_H + n]    = Whb[n];
        bias[BTAU_H + n]  = Wtauhb[n];
        bias[BH_TOT + n]  = Uhb[n] + bh[n] + CPL_ * z2hb[n];
        bias[BT_ZR + n]   = Wzrb[n];
        bias[BT_ZI + n]   = Wzib[n];
        bias[BTAU_Z + n]  = Wtauzb[n];
        bias[BZR_TOT + n] = Uzb[n] + bzr[n] + CPL_ * h2zb[n];
        bias[BZI_TOT + n] = Uzb[n] + bzi[n] + CPL_ * h2zb[n];
        if (n < 64) bias[BY + n] = ohb[n] + ozb[n];
        if (n < 16) ((unsigned*)((char*)bias + 8448))[n * 16] = 0;  // barrier counters
    }
}

// Load 8 A-fragments (K=256) for one state from swizzled LDS.
__device__ __forceinline__ void loadA8(const unsigned short* s, int m16, int hi, bf16x8* a) {
    const char* base = (const char*)s;
    const int xm = (m16 & 7) << 4;
#pragma unroll
    for (int kt = 0; kt < 8; ++kt)
        a[kt] = *(const bf16x8*)(base + ((m16 * 512 + kt * 64 + hi * 16) ^ xm));
}

// Load weight fragments (fragment-permuted ws) into registers, once.
template<int NKT>
__device__ __forceinline__ void wload(bf16x8* w, const unsigned short* __restrict__ p, int loff) {
#pragma unroll
    for (int kt = 0; kt < NKT; ++kt) w[kt] = *(const bf16x8*)(p + kt * 512 + loff);
}

// GEMM with both operands in registers.
template<int NKT>
__device__ __forceinline__ void wgemm(const bf16x8* a, const bf16x8* w, f32x4& acc) {
#pragma unroll
    for (int kt = 0; kt < NKT; ++kt)
        acc = __builtin_amdgcn_mfma_f32_16x16x32_bf16(a[kt], w[kt], acc, 0, 0, 0);
}

// x A-fragment straight from global fp32
__device__ __forceinline__ bf16x8 loadXfrag(const float* __restrict__ xrow, int off) {
    float4 v0 = *(const float4*)(xrow + off);
    float4 v1 = *(const float4*)(xrow + off + 4);
    bf16x8 r;
    r[0] = (short)f2bf(v0.x); r[1] = (short)f2bf(v0.y);
    r[2] = (short)f2bf(v0.z); r[3] = (short)f2bf(v0.w);
    r[4] = (short)f2bf(v1.x); r[5] = (short)f2bf(v1.y);
    r[6] = (short)f2bf(v1.z); r[7] = (short)f2bf(v1.w);
    return r;
}

// Publish one state's 4 rows (cols paired via shfl) as u32 agent stores in sst-image order.
__device__ __forceinline__ void publish_state(char* imgs, int hi, int m16, int npair2,
                                              const float* v) {
    const int odd = m16 & 1;
    float oth[4];
#pragma unroll
    for (int j = 0; j < 4; ++j) oth[j] = __shfl_xor(v[j], 1);
#pragma unroll
    for (int k = 0; k < 2; ++k) {
        const int j = odd * 2 + k;
        const int r = hi * 4 + j;
        unsigned a = f2bf(v[j]), b = f2bf(oth[j]);
        unsigned u = odd ? (b | (a << 16)) : (a | (b << 16));
        const int byte = (r * 512 + npair2) ^ ((r & 7) << 4);
        __hip_atomic_store((unsigned*)(imgs + byte), u, __ATOMIC_RELAXED,
                           __HIP_MEMORY_SCOPE_AGENT);
    }
}

// Passthrough read-back: 32KB image -> LDS, identical byte layout.
__device__ __forceinline__ void readback32(const unsigned long long* __restrict__ img8,
                                           char* sstb, int tid) {
#pragma unroll
    for (int i = 0; i < 32; ++i) {
        unsigned long long v = __hip_atomic_load(img8 + tid + 128 * i, __ATOMIC_RELAXED,
                                                 __HIP_MEMORY_SCOPE_AGENT);
        *(unsigned long long*)(sstb + (size_t)(tid + 128 * i) * 8) = v;
    }
}

// ---------------- main recurrent kernel ----------------
// grid: 256 blocks = 16 rowgroups x 16 col-tiles. 128 threads = 2 waves:
// wave 0 = h-path, wave 1 = z-path. ALL weights for the block's tile live in VGPRs.
// Cross-block state exchange per step via agent-scope atomics on an sst byte-image.
__launch_bounds__(128, 1)
__global__ void twistor_main(const float* __restrict__ x, unsigned short* __restrict__ ws,
                             float* __restrict__ y) {
    __shared__ unsigned short sst[4][4096];   // h, zr, zi, za [16 x 256 bf16], swizzled
    __shared__ float yslot[64][4];            // OZ partial from z-wave -> h-wave

    const int tid  = threadIdx.x;
    const int lane = tid & 63;
    const int role = tid >> 6;          // 0 = h-wave, 1 = z-wave
    const int m16  = lane & 15;
    const int hi   = lane >> 4;
    const int loff = lane * 8;
    const int bid  = blockIdx.x;
    const int rg   = bid >> 4;          // rowgroup 0..15
    const int tt   = bid & 15;          // col tile 0..15
    const int brow0 = rg * 16;
    const int n    = tt * 16 + m16;
    const int npair2 = (n & ~1) * 2;
    const float* bias = (const float*)((const char*)ws + BIAS_OFF_BYTES);
    unsigned* ctr = (unsigned*)((char*)ws + CTR_OFF_BYTES) + rg * 16;
    char* simg = (char*)ws + STATE_OFF_BYTES;

    // zero state LDS (t=0 state is all zeros)
    for (int i = tid; i < 2048; i += 128) ((unsigned long long*)sst)[i] = 0;
    __syncthreads();

    if (role == 0) {
        // =========================== h-wave ===========================
        bf16x8 wWH[8], wTAU[8], wZ2H[8], wUH[4], wOH[8];
        wload<8>(wWH,  ws + G_WH    * 65536 + tt * 4096, loff);
        wload<8>(wTAU, ws + G_WTAUH * 65536 + tt * 4096, loff);
        wload<8>(wZ2H, ws + G_Z2H   * 65536 + tt * 4096, loff);
        wload<4>(wUH,  ws + UH + tt * 2048, loff);
        if (tt < 4) wload<8>(wOH, ws + OH + tt * 4096, loff);

        const float bthh = bias[BT_H + n], btauh = bias[BTAU_H + n], bht = bias[BH_TOT + n];
        const float by_ = (tt < 4) ? bias[BY + n] : 0.f;
        float h_[4] = {0, 0, 0, 0};

        bf16x8 ax[4];
        {
            const float* xrow = x + ((size_t)brow0 + m16) * INP_;
#pragma unroll
            for (int kt = 0; kt < 4; ++kt) ax[kt] = loadXfrag(xrow, kt * 32 + hi * 8);
        }

        for (int t = 0; t < T_; ++t) {
            const int p = (t + 1) & 1;
            char* img = simg + (size_t)(p * 16 + rg) * 32768;

            bf16x8 ah[8], azr[8];
            loadA8(sst[0], m16, hi, ah);
            loadA8(sst[1], m16, hi, azr);

            f32x4 a_y = {0.f, 0.f, 0.f, 0.f};
            if (tt < 4 && t > 0) wgemm<8>(ah, wOH, a_y);

            f32x4 a_th = {0.f, 0.f, 0.f, 0.f}, a_tau = {0.f, 0.f, 0.f, 0.f};
            f32x4 a_ch = {0.f, 0.f, 0.f, 0.f};
            wgemm<8>(ah,  wWH,  a_th);
            wgemm<8>(ah,  wTAU, a_tau);
            wgemm<8>(azr, wZ2H, a_ch);
            wgemm<4>(ax,  wUH,  a_ch);

            float hn[4];
#pragma unroll
            for (int j = 0; j < 4; ++j) {
                float th = fminf(fmaxf(sigmoid_fast(a_tau[j] + btauh), 0.01f), 1.0f) + 1e-6f;
                float dh = -h_[j] + tanh_fast(a_th[j] + bthh) + a_ch[j] + bht;
                hn[j]    = h_[j] + DT_ * dh * rcp_(th);
                h_[j] = hn[j];
            }
            publish_state(img, hi, m16, npair2, hn);
            __syncthreads();   // (1) LDS reads done; publish stores drained; yslot ready

            if (tt < 4 && t > 0) {
                f32x4 yz = *(const f32x4*)yslot[lane];
#pragma unroll
                for (int j = 0; j < 4; ++j)
                    y[((size_t)(t - 1) * B_ + brow0 + hi * 4 + j) * OUT_ + n] =
                        a_y[j] + yz[j] + by_;
            }
            if (t + 1 < T_) {
                const float* xrow = x + ((size_t)(t + 1) * B_ + brow0 + m16) * INP_;
#pragma unroll
                for (int kt = 0; kt < 4; ++kt) ax[kt] = loadXfrag(xrow, kt * 32 + hi * 8);
            }
            __syncthreads();   // (2) all 16 peers published (counter checked by z-wave)

            readback32((const unsigned long long*)img, (char*)sst, tid);
            __syncthreads();   // (3) sst ready for next step
        }

        // final y_{T-1} from S_T
        f32x4 a_y = {0.f, 0.f, 0.f, 0.f};
        if (tt < 4) {
            bf16x8 ah[8];
            loadA8(sst[0], m16, hi, ah);
            wgemm<8>(ah, wOH, a_y);
        }
        __syncthreads();       // (F)
        if (tt < 4) {
            f32x4 yz = *(const f32x4*)yslot[lane];
#pragma unroll
            for (int j = 0; j < 4; ++j)
                y[((size_t)(T_ - 1) * B_ + brow0 + hi * 4 + j) * OUT_ + n] =
                    a_y[j] + yz[j] + by_;
        }
    } else {
        // =========================== z-wave ===========================
        bf16x8 wWZR[8], wWZI[8], wWTZ[8], wH2Z[8], wUZ[4], wOZ[8];
        wload<8>(wWZR, ws + G_WZR   * 65536 + tt * 4096, loff);
        wload<8>(wWZI, ws + G_WZI   * 65536 + tt * 4096, loff);
        wload<8>(wWTZ, ws + G_WTAUZ * 65536 + tt * 4096, loff);
        wload<8>(wH2Z, ws + G_H2Z   * 65536 + tt * 4096, loff);
        wload<4>(wUZ,  ws + UZ + tt * 2048, loff);
        if (tt < 4) wload<8>(wOZ, ws + OZ + tt * 4096, loff);

        const float btzr = bias[BT_ZR + n], btzi = bias[BT_ZI + n], btauz = bias[BTAU_Z + n];
        const float bzrt = bias[BZR_TOT + n], bzit = bias[BZI_TOT + n];
        float zr_[4] = {0, 0, 0, 0}, zi_[4] = {0, 0, 0, 0};

        bf16x8 ax[4];
        {
            const float* xrow = x + ((size_t)brow0 + m16) * INP_;
#pragma unroll
            for (int kt = 0; kt < 4; ++kt) ax[kt] = loadXfrag(xrow, kt * 32 + hi * 8);
        }

        for (int t = 0; t < T_; ++t) {
            const int p = (t + 1) & 1;
            char* img = simg + (size_t)(p * 16 + rg) * 32768;

            bf16x8 ah[8], azr[8];
            loadA8(sst[0], m16, hi, ah);
            loadA8(sst[1], m16, hi, azr);

            f32x4 a_y = {0.f, 0.f, 0.f, 0.f};
            if (tt < 4 && t > 0) {
                wgemm<8>(azr, wOZ, a_y);
                *(f32x4*)yslot[lane] = a_y;
            }

            f32x4 a_tzr = {0.f, 0.f, 0.f, 0.f}, a_tzi = {0.f, 0.f, 0.f, 0.f};
            f32x4 a_tz  = {0.f, 0.f, 0.f, 0.f}, a_cz  = {0.f, 0.f, 0.f, 0.f};
            wgemm<8>(azr, wWZR, a_tzr);
            wgemm<8>(ah,  wH2Z, a_cz);
            {
                bf16x8 azi[8];
                loadA8(sst[2], m16, hi, azi);
                wgemm<8>(azi, wWZI, a_tzi);
            }
            {
                bf16x8 aza[8];
                loadA8(sst[3], m16, hi, aza);
                wgemm<8>(aza, wWTZ, a_tz);
            }
            wgemm<4>(ax, wUZ, a_cz);

            float zrn[4], zin[4], zan[4];
#pragma unroll
            for (int j = 0; j < 4; ++j) {
                float tz  = fminf(fmaxf(sigmoid_fast(a_tz[j] + btauz), 0.01f), 1.0f) + 1e-6f;
                float rtz = rcp_(tz);
                float dzr = -zr_[j] + tanh_fast(a_tzr[j] + btzr) + a_cz[j] + bzrt;
                float dzi = -zi_[j] + tanh_fast(a_tzi[j] + btzi) + a_cz[j] + bzit;
                zrn[j] = zr_[j] + DT_ * dzr * rtz;
                zin[j] = zi_[j] + DT_ * dzi * rtz;
                zan[j] = sqrtf(zrn[j] * zrn[j] + zin[j] * zin[j] + 1e-24f);
                zr_[j] = zrn[j]; zi_[j] = zin[j];
            }
            publish_state(img + 8192,  hi, m16, npair2, zrn);
            publish_state(img + 16384, hi, m16, npair2, zin);
            publish_state(img + 24576, hi, m16, npair2, zan);
            __syncthreads();   // (1)

            if (t + 1 < T_) {
                const float* xrow = x + ((size_t)(t + 1) * B_ + brow0 + m16) * INP_;
#pragma unroll
                for (int kt = 0; kt < 4; ++kt) ax[kt] = loadXfrag(xrow, kt * 32 + hi * 8);
            }
            if (tid == 127) {
                __hip_atomic_fetch_add(ctr, 1u, __ATOMIC_RELAXED, __HIP_MEMORY_SCOPE_AGENT);
                const unsigned tgt = 16u * (unsigned)(t + 1);
                while (__hip_atomic_load(ctr, __ATOMIC_RELAXED, __HIP_MEMORY_SCOPE_AGENT) < tgt)
                    __builtin_amdgcn_s_sleep(2);
            }
            __syncthreads();   // (2)

            readback32((const unsigned long long*)img, (char*)sst, tid);
            __syncthreads();   // (3)
        }

        // final y partial (OZ) for y_{T-1}
        if (tt < 4) {
            bf16x8 azr[8];
            loadA8(sst[1], m16, hi, azr);
            f32x4 a_y = {0.f, 0.f, 0.f, 0.f};
            wgemm<8>(azr, wOZ, a_y);
            *(f32x4*)yslot[lane] = a_y;
        }
        __syncthreads();       // (F)
    }
}

extern "C" void kernel_launch(void* const* d_in, const int* in_sizes, int n_in,
                              void* d_out, int out_size, void* d_ws, size_t ws_size,
                              hipStream_t stream) {
    const float* x = (const float*)d_in[0];
    unsigned short* ws = (unsigned short*)d_ws;
    float* bias = (float*)((char*)d_ws + BIAS_OFF_BYTES);

    prep_weights<<<(NW_TOTAL / 8 + 255) / 256, 256, 0, stream>>>(
        (const float*)d_in[1],  /* W_h_w */
        (const float*)d_in[5],  /* W_tau_h_w */
        (const float*)d_in[8],  /* W_z_real_w */
        (const float*)d_in[10], /* W_z_imag_w */
        (const float*)d_in[14], /* W_tau_z_w */
        (const float*)d_in[18], /* h2z_w */
        (const float*)d_in[20], /* z2h_w */
        (const float*)d_in[3],  /* U_h_w */
        (const float*)d_in[12], /* U_z_w */
        (const float*)d_in[22], /* out_h_w */
        (const float*)d_in[24], /* out_z_w */
        ws);
    prep_bias<<<1, 256, 0, stream>>>(
        (const float*)d_in[2],  /* W_h_b */
        (const float*)d_in[6],  /* W_tau_h_b */
        (const float*)d_in[4],  /* U_h_b */
        (const float*)d_in[7],  /* b_h */
        (const float*)d_in[21], /* z2h_b */
        (const float*)d_in[9],  /* W_z_real_b */
        (const float*)d_in[11], /* W_z_imag_b */
        (const float*)d_in[15], /* W_tau_z_b */
        (const float*)d_in[13], /* U_z_b */
        (const float*)d_in[16], /* b_z_real */
        (const float*)d_in[17], /* b_z_imag */
        (const float*)d_in[19], /* h2z_b */
        (const float*)d_in[23], /* out_h_b */
        (const float*)d_in[25], /* out_z_b */
        bias);
    twistor_main<<<256, 128, 0, stream>>>(x, ws, (float*)d_out);
}

// Round 8
// 4112.712 us; speedup vs baseline: 1.4068x; 1.4068x over previous
//
#include <hip/hip_runtime.h>
#include <hip/hip_bf16.h>
#include <math.h>

// ---------------- problem constants ----------------
#define T_    512
#define B_    256
#define INP_  128
#define HID_  256
#define OUT_  64
#define DT_   0.1f
#define CPL_  0.1f

typedef __attribute__((ext_vector_type(8))) short          bf16x8;
typedef __attribute__((ext_vector_type(4))) float          f32x4;
typedef __attribute__((ext_vector_type(4))) unsigned short u16x4;

// ---------------- ws layout (ushort units, FRAGMENT-PERMUTED) ----------------
#define G_WH    0
#define G_WTAUH 1
#define G_WZR   2
#define G_WZI   3
#define G_WTAUZ 4
#define G_H2Z   5
#define G_Z2H   6
#define UH     458752   // 7*65536
#define UZ     491520
#define OH     524288
#define OZ     540672
#define NW_TOTAL 557056
#define BIAS_OFF_BYTES (NW_TOTAL * 2)
#define BT_H    0
#define BTAU_H  256
#define BH_TOT  512
#define BT_ZR   768
#define BT_ZI   1024
#define BTAU_Z  1280
#define BZR_TOT 1536
#define BZI_TOT 1792
#define BY      2048   // 64 floats
#define CTR_OFF_BYTES   (BIAS_OFF_BYTES + 8448)   // 16 counters, 64B apart
#define STATE_OFF_BYTES (CTR_OFF_BYTES + 1024)
// state image: [parity2][rg16][32768 B] -- exact byte-image of sst (4 states x 8192B,
// XOR-swizzled). Publishers scatter u32 col-pairs (round-6 proven); readers passthrough.

// fp32 -> bf16, round-to-nearest-even
__device__ __forceinline__ unsigned short f2bf(float f) {
    unsigned int u = __float_as_uint(f);
    u += 0x7fffu + ((u >> 16) & 1u);
    return (unsigned short)(u >> 16);
}

__device__ __forceinline__ float rcp_(float x) { return __builtin_amdgcn_rcpf(x); }
__device__ __forceinline__ float sigmoid_fast(float x) {
    return rcp_(1.0f + __expf(-x));
}
__device__ __forceinline__ float tanh_fast(float x) {
    return 1.0f - 2.0f * rcp_(__expf(2.0f * x) + 1.0f);
}

// ---------------- prep: weights fp32 -> bf16, fragment-permuted ----------------
__global__ void prep_weights(const float* __restrict__ Wh,   const float* __restrict__ Wtauh,
                             const float* __restrict__ Wzr,  const float* __restrict__ Wzi,
                             const float* __restrict__ Wtauz,const float* __restrict__ h2z,
                             const float* __restrict__ z2h,  const float* __restrict__ Uh,
                             const float* __restrict__ Uz,   const float* __restrict__ oh,
                             const float* __restrict__ oz,   unsigned short* __restrict__ ws) {
    int fid = blockIdx.x * 256 + threadIdx.x;   // one 8-elem fragment per thread
    if (fid >= NW_TOTAL / 8) return;
    int o = fid * 8;
    const float* src;
    int row, col, K;
    float scale = 1.0f;
    if (o < UH) {                       // H region, K=256
        int g  = o >> 16;
        int r  = o & 65535;
        int T  = r >> 12;
        int r2 = r & 4095;
        int kt = r2 >> 9;
        int l  = (r2 & 511) >> 3;
        row = T * 16 + (l & 15);
        col = kt * 32 + (l >> 4) * 8;
        K = 256;
        if      (g == G_WH)    src = Wh;
        else if (g == G_WTAUH) src = Wtauh;
        else if (g == G_WZR)   src = Wzr;
        else if (g == G_WZI)   src = Wzi;
        else if (g == G_WTAUZ) src = Wtauz;
        else if (g == G_H2Z)   { src = h2z; scale = CPL_; }
        else                   { src = z2h; scale = CPL_; }
    } else if (o < OH) {                // U region, K=128
        int g  = (o - UH) >> 15;
        int r  = (o - UH) & 32767;
        int T  = r >> 11;
        int r2 = r & 2047;
        int kt = r2 >> 9;
        int l  = (r2 & 511) >> 3;
        row = T * 16 + (l & 15);
        col = kt * 32 + (l >> 4) * 8;
        K = 128;
        src = g ? Uz : Uh;
    } else {                            // OUT region, K=256
        int g  = (o - OH) >> 14;
        int r  = (o - OH) & 16383;
        int T  = r >> 12;
        int r2 = r & 4095;
        int kt = r2 >> 9;
        int l  = (r2 & 511) >> 3;
        row = T * 16 + (l & 15);
        col = kt * 32 + (l >> 4) * 8;
        K = 256;
        src = g ? oz : oh;
    }
    const float* p = src + (size_t)row * K + col;
    float4 v0 = *(const float4*)p;
    float4 v1 = *(const float4*)(p + 4);
    u16x4 a, b;
    a.x = f2bf(v0.x * scale); a.y = f2bf(v0.y * scale);
    a.z = f2bf(v0.z * scale); a.w = f2bf(v0.w * scale);
    b.x = f2bf(v1.x * scale); b.y = f2bf(v1.y * scale);
    b.z = f2bf(v1.z * scale); b.w = f2bf(v1.w * scale);
    *(u16x4*)(ws + o)     = a;
    *(u16x4*)(ws + o + 4) = b;
}

// ---------------- prep: folded biases (fp32) + zero barrier counters ----------------
__global__ void prep_bias(const float* __restrict__ Whb,  const float* __restrict__ Wtauhb,
                          const float* __restrict__ Uhb,  const float* __restrict__ bh,
                          const float* __restrict__ z2hb, const float* __restrict__ Wzrb,
                          const float* __restrict__ Wzib, const float* __restrict__ Wtauzb,
                          const float* __restrict__ Uzb,  const float* __restrict__ bzr,
                          const float* __restrict__ bzi,  const float* __restrict__ h2zb,
                          const float* __restrict__ ohb,  const float* __restrict__ ozb,
                          float* __restrict__ bias) {
    int n = threadIdx.x;
    if (n < 256) {
        bias[BT_H + n]    = Whb[n];
        bias[BTAU_H + n]  = Wtauhb[n];
        bias[BH_TOT + n]  = Uhb[n] + bh[n] + CPL_ * z2hb[n];
        bias[BT_ZR + n]   = Wzrb[n];
        bias[BT_ZI + n]   = Wzib[n];
        bias[BTAU_Z + n]  = Wtauzb[n];
        bias[BZR_TOT + n] = Uzb[n] + bzr[n] + CPL_ * h2zb[n];
        bias[BZI_TOT + n] = Uzb[n] + bzi[n] + CPL_ * h2zb[n];
        if (n < 64) bias[BY + n] = ohb[n] + ozb[n];
        if (n < 16) ((unsigned*)((char*)bias + 8448))[n * 16] = 0;  // barrier counters
    }
}

// Load 8 A-fragments (K=256) for one state from swizzled LDS.
__device__ __forceinline__ void loadA8(const unsigned short* s, int m16, int hi, bf16x8* a) {
    const char* base = (const char*)s;
    const int xm = (m16 & 7) << 4;
#pragma unroll
    for (int kt = 0; kt < 8; ++kt)
        a[kt] = *(const bf16x8*)(base + ((m16 * 512 + kt * 64 + hi * 16) ^ xm));
}

// Load weight fragments (fragment-permuted ws) into registers, once.
template<int NKT>
__device__ __forceinline__ void wload(bf16x8* w, const unsigned short* __restrict__ p, int loff) {
#pragma unroll
    for (int kt = 0; kt < NKT; ++kt) w[kt] = *(const bf16x8*)(p + kt * 512 + loff);
}

// GEMM with both operands in registers.
template<int NKT>
__device__ __forceinline__ void wgemm(const bf16x8* a, const bf16x8* w, f32x4& acc) {
#pragma unroll
    for (int kt = 0; kt < NKT; ++kt)
        acc = __builtin_amdgcn_mfma_f32_16x16x32_bf16(a[kt], w[kt], acc, 0, 0, 0);
}

// x A-fragment straight from global fp32
__device__ __forceinline__ bf16x8 loadXfrag(const float* __restrict__ xrow, int off) {
    float4 v0 = *(const float4*)(xrow + off);
    float4 v1 = *(const float4*)(xrow + off + 4);
    bf16x8 r;
    r[0] = (short)f2bf(v0.x); r[1] = (short)f2bf(v0.y);
    r[2] = (short)f2bf(v0.z); r[3] = (short)f2bf(v0.w);
    r[4] = (short)f2bf(v1.x); r[5] = (short)f2bf(v1.y);
    r[6] = (short)f2bf(v1.z); r[7] = (short)f2bf(v1.w);
    return r;
}

// ROUND-6 PROVEN: publish one state's 4 rows (cols paired via shfl) as u32 agent
// stores in sst-image (swizzled) order. imgs = image base of this state (8KB region).
__device__ __forceinline__ void publish_state(char* imgs, int hi, int m16, int npair2,
                                              const float* v) {
    const int odd = m16 & 1;
    float oth[4];
#pragma unroll
    for (int j = 0; j < 4; ++j) oth[j] = __shfl_xor(v[j], 1);
#pragma unroll
    for (int k = 0; k < 2; ++k) {
        const int j = odd * 2 + k;
        const int r = hi * 4 + j;
        unsigned a = f2bf(v[j]), b = f2bf(oth[j]);
        unsigned u = odd ? (b | (a << 16)) : (a | (b << 16));
        const int byte = (r * 512 + npair2) ^ ((r & 7) << 4);
        __hip_atomic_store((unsigned*)(imgs + byte), u, __ATOMIC_RELAXED,
                           __HIP_MEMORY_SCOPE_AGENT);
    }
}

// ---------------- main recurrent kernel ----------------
// grid: 128 blocks = 16 rowgroups x 8 colgroups. 256 threads = 4 waves:
// wave w: tile tt = 2*cg + (w>>1), role (w&1): 0 = h-path, 1 = z-path.
// ALL weights for the wave's tile+role live in registers (loaded once).
// Exchange: round-6-proven byte-image scatter publish + passthrough readback.
__launch_bounds__(256, 1)
__global__ void twistor_main(const float* __restrict__ x, unsigned short* __restrict__ ws,
                             float* __restrict__ y) {
    __shared__ unsigned short sst[4][4096];   // h, zr, zi, za [16 x 256 bf16], swizzled
    __shared__ float yslot[2][64][4];         // OZ partial from z-wave -> h-wave (per tile)

    const int tid  = threadIdx.x;
    const int lane = tid & 63;
    const int w    = tid >> 6;          // 0..3
    const int half = w >> 1;            // tile within block: 0/1
    const int role = w & 1;             // 0 = h-wave, 1 = z-wave
    const int m16  = lane & 15;
    const int hi   = lane >> 4;
    const int loff = lane * 8;
    const int bid  = blockIdx.x;
    const int rg   = bid >> 3;          // rowgroup 0..15
    const int cg   = bid & 7;           // colgroup 0..7
    const int tt   = cg * 2 + half;     // this wave's col tile 0..15
    const int brow0 = rg * 16;
    const int n    = tt * 16 + m16;
    const int npair2 = (n & ~1) * 2;
    const float* bias = (const float*)((const char*)ws + BIAS_OFF_BYTES);
    unsigned* ctr = (unsigned*)((char*)ws + CTR_OFF_BYTES) + rg * 16;
    char* simg = (char*)ws + STATE_OFF_BYTES;

    // zero ALL state LDS (t=0 state is all zeros) -- 4096 u64 = full 32KB
    for (int i = tid; i < 4096; i += 256) ((unsigned long long*)sst)[i] = 0;
    __syncthreads();

    // ---- per-wave weight registers ----
    bf16x8 wA[8], wB[8], wC[8], wU[4], wO[8];   // role-dependent meaning
    if (role == 0) {
        wload<8>(wA, ws + G_WH    * 65536 + tt * 4096, loff);   // WH
        wload<8>(wB, ws + G_WTAUH * 65536 + tt * 4096, loff);   // WTAUH
        wload<8>(wC, ws + G_Z2H   * 65536 + tt * 4096, loff);   // Z2H*CPL
        wload<4>(wU, ws + UH + tt * 2048, loff);                // UH
        if (tt < 4) wload<8>(wO, ws + OH + tt * 4096, loff);    // OH
    } else {
        wload<8>(wA, ws + G_WZR   * 65536 + tt * 4096, loff);   // WZR
        wload<8>(wB, ws + G_WZI   * 65536 + tt * 4096, loff);   // WZI
        wload<8>(wC, ws + G_H2Z   * 65536 + tt * 4096, loff);   // H2Z*CPL
        wload<4>(wU, ws + UZ + tt * 2048, loff);                // UZ
        if (tt < 4) wload<8>(wO, ws + OZ + tt * 4096, loff);    // OZ
    }
    bf16x8 wTZ[8];
    if (role == 1) wload<8>(wTZ, ws + G_WTAUZ * 65536 + tt * 4096, loff);

    const float bthh = bias[BT_H + n],    btauh = bias[BTAU_H + n], bht = bias[BH_TOT + n];
    const float btzr = bias[BT_ZR + n],   btzi  = bias[BT_ZI + n],  btauz = bias[BTAU_Z + n];
    const float bzrt = bias[BZR_TOT + n], bzit  = bias[BZI_TOT + n];
    const float by_  = (tt < 4 && role == 0) ? bias[BY + n] : 0.f;

    float s0_[4] = {0, 0, 0, 0};   // role 0: h ; role 1: zr
    float s1_[4] = {0, 0, 0, 0};   // role 1: zi (unused for role 0)

    bf16x8 ax[4];
    {
        const float* xrow = x + ((size_t)brow0 + m16) * INP_;
#pragma unroll
        for (int kt = 0; kt < 4; ++kt) ax[kt] = loadXfrag(xrow, kt * 32 + hi * 8);
    }

    for (int t = 0; t < T_; ++t) {
        const int p = (t + 1) & 1;
        char* img = simg + (size_t)(p * 16 + rg) * 32768;

        bf16x8 ah[8], azr[8];
        loadA8(sst[0], m16, hi, ah);
        loadA8(sst[1], m16, hi, azr);

        f32x4 a_y = {0.f, 0.f, 0.f, 0.f};
        if (tt < 4 && t > 0) {
            if (role == 0) {
                wgemm<8>(ah, wO, a_y);
            } else {
                wgemm<8>(azr, wO, a_y);
                *(f32x4*)yslot[half][lane] = a_y;
            }
        }

        if (role == 0) {
            // ---- h-path ----
            f32x4 a_th = {0.f, 0.f, 0.f, 0.f}, a_tau = {0.f, 0.f, 0.f, 0.f};
            f32x4 a_ch = {0.f, 0.f, 0.f, 0.f};
            wgemm<8>(ah,  wA, a_th);
            wgemm<8>(ah,  wB, a_tau);
            wgemm<8>(azr, wC, a_ch);
            wgemm<4>(ax,  wU, a_ch);
            float hn[4];
#pragma unroll
            for (int j = 0; j < 4; ++j) {
                float th = fminf(fmaxf(sigmoid_fast(a_tau[j] + btauh), 0.01f), 1.0f) + 1e-6f;
                float dh = -s0_[j] + tanh_fast(a_th[j] + bthh) + a_ch[j] + bht;
                hn[j]    = s0_[j] + DT_ * dh * rcp_(th);
                s0_[j] = hn[j];
            }
            publish_state(img, hi, m16, npair2, hn);                 // state 0 (h)
        } else {
            // ---- z-path ----
            f32x4 a_tzr = {0.f, 0.f, 0.f, 0.f}, a_tzi = {0.f, 0.f, 0.f, 0.f};
            f32x4 a_tz  = {0.f, 0.f, 0.f, 0.f}, a_cz  = {0.f, 0.f, 0.f, 0.f};
            wgemm<8>(azr, wA, a_tzr);
            wgemm<8>(ah,  wC, a_cz);
            {
                bf16x8 azi[8];
                loadA8(sst[2], m16, hi, azi);
                wgemm<8>(azi, wB, a_tzi);
            }
            {
                bf16x8 aza[8];
                loadA8(sst[3], m16, hi, aza);
                wgemm<8>(aza, wTZ, a_tz);
            }
            wgemm<4>(ax, wU, a_cz);
            float zrn[4], zin[4], zan[4];
#pragma unroll
            for (int j = 0; j < 4; ++j) {
                float tz  = fminf(fmaxf(sigmoid_fast(a_tz[j] + btauz), 0.01f), 1.0f) + 1e-6f;
                float rtz = rcp_(tz);
                float dzr = -s0_[j] + tanh_fast(a_tzr[j] + btzr) + a_cz[j] + bzrt;
                float dzi = -s1_[j] + tanh_fast(a_tzi[j] + btzi) + a_cz[j] + bzit;
                zrn[j] = s0_[j] + DT_ * dzr * rtz;
                zin[j] = s1_[j] + DT_ * dzi * rtz;
                zan[j] = sqrtf(zrn[j] * zrn[j] + zin[j] * zin[j] + 1e-24f);
                s0_[j] = zrn[j]; s1_[j] = zin[j];
            }
            publish_state(img + 8192,  hi, m16, npair2, zrn);        // state 1 (zr)
            publish_state(img + 16384, hi, m16, npair2, zin);        // state 2 (zi)
            publish_state(img + 24576, hi, m16, npair2, zan);        // state 3 (za)
        }
        __syncthreads();   // (1) LDS reads done; publish stores drained; yslot ready

        // ---- overlap window: y store, x prefetch, counter arrive+wait ----
        if (tt < 4 && role == 0 && t > 0) {
            f32x4 yz = *(const f32x4*)yslot[half][lane];
#pragma unroll
            for (int j = 0; j < 4; ++j)
                y[((size_t)(t - 1) * B_ + brow0 + hi * 4 + j) * OUT_ + n] =
                    a_y[j] + yz[j] + by_;
        }
        if (t + 1 < T_) {
            const float* xrow = x + ((size_t)(t + 1) * B_ + brow0 + m16) * INP_;
#pragma unroll
            for (int kt = 0; kt < 4; ++kt) ax[kt] = loadXfrag(xrow, kt * 32 + hi * 8);
        }
        if (tid == 255) {
            __hip_atomic_fetch_add(ctr, 1u, __ATOMIC_RELAXED, __HIP_MEMORY_SCOPE_AGENT);
            const unsigned tgt = 8u * (unsigned)(t + 1);
            while (__hip_atomic_load(ctr, __ATOMIC_RELAXED, __HIP_MEMORY_SCOPE_AGENT) < tgt)
                __builtin_amdgcn_s_sleep(2);
        }
        __syncthreads();   // (2) all 8 peers published

        // ---- passthrough read-back: 32KB image -> sst, identical byte layout ----
        {
            const unsigned long long* img8 = (const unsigned long long*)img;
            char* sstb = (char*)sst;
#pragma unroll
            for (int i = 0; i < 16; ++i) {
                unsigned long long v = __hip_atomic_load(img8 + tid + 256 * i,
                                                         __ATOMIC_RELAXED,
                                                         __HIP_MEMORY_SCOPE_AGENT);
                *(unsigned long long*)(sstb + (size_t)(tid + 256 * i) * 8) = v;
            }
        }
        __syncthreads();   // (3) sst ready for next step
    }

    // final y_{T-1} from S_T (staged in sst by last exchange)
    {
        f32x4 a_y = {0.f, 0.f, 0.f, 0.f};
        if (tt < 4) {
            if (role == 0) {
                bf16x8 ah[8];
                loadA8(sst[0], m16, hi, ah);
                wgemm<8>(ah, wO, a_y);
            } else {
                bf16x8 azr[8];
                loadA8(sst[1], m16, hi, azr);
                wgemm<8>(azr, wO, a_y);
                *(f32x4*)yslot[half][lane] = a_y;
            }
        }
        __syncthreads();
        if (tt < 4 && role == 0) {
            f32x4 yz = *(const f32x4*)yslot[half][lane];
#pragma unroll
            for (int j = 0; j < 4; ++j)
                y[((size_t)(T_ - 1) * B_ + brow0 + hi * 4 + j) * OUT_ + n] =
                    a_y[j] + yz[j] + by_;
        }
    }
}

extern "C" void kernel_launch(void* const* d_in, const int* in_sizes, int n_in,
                              void* d_out, int out_size, void* d_ws, size_t ws_size,
                              hipStream_t stream) {
    const float* x = (const float*)d_in[0];
    unsigned short* ws = (unsigned short*)d_ws;
    float* bias = (float*)((char*)d_ws + BIAS_OFF_BYTES);

    prep_weights<<<(NW_TOTAL / 8 + 255) / 256, 256, 0, stream>>>(
        (const float*)d_in[1],  /* W_h_w */
        (const float*)d_in[5],  /* W_tau_h_w */
        (const float*)d_in[8],  /* W_z_real_w */
        (const float*)d_in[10], /* W_z_imag_w */
        (const float*)d_in[14], /* W_tau_z_w */
        (const float*)d_in[18], /* h2z_w */
        (const float*)d_in[20], /* z2h_w */
        (const float*)d_in[3],  /* U_h_w */
        (const float*)d_in[12], /* U_z_w */
        (const float*)d_in[22], /* out_h_w */
        (const float*)d_in[24], /* out_z_w */
        ws);
    prep_bias<<<1, 256, 0, stream>>>(
        (const float*)d_in[2],  /* W_h_b */
        (const float*)d_in[6],  /* W_tau_h_b */
        (const float*)d_in[4],  /* U_h_b */
        (const float*)d_in[7],  /* b_h */
        (const float*)d_in[21], /* z2h_b */
        (const float*)d_in[9],  /* W_z_real_b */
        (const float*)d_in[11], /* W_z_imag_b */
        (const float*)d_in[15], /* W_tau_z_b */
        (const float*)d_in[13], /* U_z_b */
        (const float*)d_in[16], /* b_z_real */
        (const float*)d_in[17], /* b_z_imag */
        (const float*)d_in[19], /* h2z_b */
        (const float*)d_in[23], /* out_h_b */
        (const float*)d_in[25], /* out_z_b */
        bias);
    twistor_main<<<128, 256, 0, stream>>>(x, ws, (float*)d_out);
}

// Round 9
// 3193.783 us; speedup vs baseline: 1.8116x; 1.2877x over previous
//
#include <hip/hip_runtime.h>
#include <hip/hip_bf16.h>
#include <math.h>

// ---------------- problem constants ----------------
#define T_    512
#define B_    256
#define INP_  128
#define HID_  256
#define OUT_  64
#define DT_   0.1f
#define CPL_  0.1f

typedef __attribute__((ext_vector_type(8))) short          bf16x8;
typedef __attribute__((ext_vector_type(4))) float          f32x4;
typedef __attribute__((ext_vector_type(4))) unsigned short u16x4;

// ---------------- ws layout (ushort units, FRAGMENT-PERMUTED) ----------------
#define G_WH    0
#define G_WTAUH 1
#define G_WZR   2
#define G_WZI   3
#define G_WTAUZ 4
#define G_H2Z   5
#define G_Z2H   6
#define UH     458752   // 7*65536
#define UZ     491520
#define OH     524288
#define OZ     540672
#define NW_TOTAL 557056
#define BIAS_OFF_BYTES (NW_TOTAL * 2)
#define BT_H    0
#define BTAU_H  256
#define BH_TOT  512
#define BT_ZR   768
#define BT_ZI   1024
#define BTAU_Z  1280
#define BZR_TOT 1536
#define BZI_TOT 1792
#define BY      2048   // 64 floats
#define CTR_OFF_BYTES   (BIAS_OFF_BYTES + 8448)   // 16 counters, 64B apart
#define STATE_OFF_BYTES (CTR_OFF_BYTES + 1024)
// state image: [parity2][rg16][tile16][state4][512B]; within a state-slot:
// u64 index = localcol*4 + q, packing rows 4q..4q+3 (bf16, bits 16e = row 4q+e).

// fp32 -> bf16, round-to-nearest-even
__device__ __forceinline__ unsigned short f2bf(float f) {
    unsigned int u = __float_as_uint(f);
    u += 0x7fffu + ((u >> 16) & 1u);
    return (unsigned short)(u >> 16);
}

__device__ __forceinline__ float rcp_(float x) { return __builtin_amdgcn_rcpf(x); }
__device__ __forceinline__ float sigmoid_fast(float x) {
    return rcp_(1.0f + __expf(-x));
}
__device__ __forceinline__ float tanh_fast(float x) {
    return 1.0f - 2.0f * rcp_(__expf(2.0f * x) + 1.0f);
}

// ---------------- prep: weights fp32 -> bf16, fragment-permuted ----------------
__global__ void prep_weights(const float* __restrict__ Wh,   const float* __restrict__ Wtauh,
                             const float* __restrict__ Wzr,  const float* __restrict__ Wzi,
                             const float* __restrict__ Wtauz,const float* __restrict__ h2z,
                             const float* __restrict__ z2h,  const float* __restrict__ Uh,
                             const float* __restrict__ Uz,   const float* __restrict__ oh,
                             const float* __restrict__ oz,   unsigned short* __restrict__ ws) {
    int fid = blockIdx.x * 256 + threadIdx.x;   // one 8-elem fragment per thread
    if (fid >= NW_TOTAL / 8) return;
    int o = fid * 8;
    const float* src;
    int row, col, K;
    float scale = 1.0f;
    if (o < UH) {                       // H region, K=256
        int g  = o >> 16;
        int r  = o & 65535;
        int T  = r >> 12;
        int r2 = r & 4095;
        int kt = r2 >> 9;
        int l  = (r2 & 511) >> 3;
        row = T * 16 + (l & 15);
        col = kt * 32 + (l >> 4) * 8;
        K = 256;
        if      (g == G_WH)    src = Wh;
        else if (g == G_WTAUH) src = Wtauh;
        else if (g == G_WZR)   src = Wzr;
        else if (g == G_WZI)   src = Wzi;
        else if (g == G_WTAUZ) src = Wtauz;
        else if (g == G_H2Z)   { src = h2z; scale = CPL_; }
        else                   { src = z2h; scale = CPL_; }
    } else if (o < OH) {                // U region, K=128
        int g  = (o - UH) >> 15;
        int r  = (o - UH) & 32767;
        int T  = r >> 11;
        int r2 = r & 2047;
        int kt = r2 >> 9;
        int l  = (r2 & 511) >> 3;
        row = T * 16 + (l & 15);
        col = kt * 32 + (l >> 4) * 8;
        K = 128;
        src = g ? Uz : Uh;
    } else {                            // OUT region, K=256
        int g  = (o - OH) >> 14;
        int r  = (o - OH) & 16383;
        int T  = r >> 12;
        int r2 = r & 4095;
        int kt = r2 >> 9;
        int l  = (r2 & 511) >> 3;
        row = T * 16 + (l & 15);
        col = kt * 32 + (l >> 4) * 8;
        K = 256;
        src = g ? oz : oh;
    }
    const float* p = src + (size_t)row * K + col;
    float4 v0 = *(const float4*)p;
    float4 v1 = *(const float4*)(p + 4);
    u16x4 a, b;
    a.x = f2bf(v0.x * scale); a.y = f2bf(v0.y * scale);
    a.z = f2bf(v0.z * scale); a.w = f2bf(v0.w * scale);
    b.x = f2bf(v1.x * scale); b.y = f2bf(v1.y * scale);
    b.z = f2bf(v1.z * scale); b.w = f2bf(v1.w * scale);
    *(u16x4*)(ws + o)     = a;
    *(u16x4*)(ws + o + 4) = b;
}

// ---------------- prep: folded biases (fp32) + zero barrier counters ----------------
__global__ void prep_bias(const float* __restrict__ Whb,  const float* __restrict__ Wtauhb,
                          const float* __restrict__ Uhb,  const float* __restrict__ bh,
                          const float* __restrict__ z2hb, const float* __restrict__ Wzrb,
                          const float* __restrict__ Wzib, const float* __restrict__ Wtauzb,
                          const float* __restrict__ Uzb,  const float* __restrict__ bzr,
                          const float* __restrict__ bzi,  const float* __restrict__ h2zb,
                          const float* __restrict__ ohb,  const float* __restrict__ ozb,
                          float* __restrict__ bias) {
    int n = threadIdx.x;
    if (n < 256) {
        bias[BT_H + n]    = Whb[n];
        bias[BTAU_H + n]  = Wtauhb[n];
        bias[BH_TOT + n]  = Uhb[n] + bh[n] + CPL_ * z2hb[n];
        bias[BT_ZR + n]   = Wzrb[n];
        bias[BT_ZI + n]   = Wzib[n];
        bias[BTAU_Z + n]  = Wtauzb[n];
        bias[BZR_TOT + n] = Uzb[n] + bzr[n] + CPL_ * h2zb[n];
        bias[BZI_TOT + n] = Uzb[n] + bzi[n] + CPL_ * h2zb[n];
        if (n < 64) bias[BY + n] = ohb[n] + ozb[n];
        if (n < 16) ((unsigned*)((char*)bias + 8448))[n * 16] = 0;  // barrier counters
    }
}

// Load 8 A-fragments (K=256) for one state from swizzled LDS.
__device__ __forceinline__ void loadA8(const unsigned short* s, int m16, int hi, bf16x8* a) {
    const char* base = (const char*)s;
    const int xm = (m16 & 7) << 4;
#pragma unroll
    for (int kt = 0; kt < 8; ++kt)
        a[kt] = *(const bf16x8*)(base + ((m16 * 512 + kt * 64 + hi * 16) ^ xm));
}

// Load weight fragments (fragment-permuted ws) into registers, once.
template<int NKT>
__device__ __forceinline__ void wload(bf16x8* w, const unsigned short* __restrict__ p, int loff) {
#pragma unroll
    for (int kt = 0; kt < NKT; ++kt) w[kt] = *(const bf16x8*)(p + kt * 512 + loff);
}

// GEMM with both operands in registers.
template<int NKT>
__device__ __forceinline__ void wgemm(const bf16x8* a, const bf16x8* w, f32x4& acc) {
#pragma unroll
    for (int kt = 0; kt < NKT; ++kt)
        acc = __builtin_amdgcn_mfma_f32_16x16x32_bf16(a[kt], w[kt], acc, 0, 0, 0);
}

// x A-fragment straight from global fp32
__device__ __forceinline__ bf16x8 loadXfrag(const float* __restrict__ xrow, int off) {
    float4 v0 = *(const float4*)(xrow + off);
    float4 v1 = *(const float4*)(xrow + off + 4);
    bf16x8 r;
    r[0] = (short)f2bf(v0.x); r[1] = (short)f2bf(v0.y);
    r[2] = (short)f2bf(v0.z); r[3] = (short)f2bf(v0.w);
    r[4] = (short)f2bf(v1.x); r[5] = (short)f2bf(v1.y);
    r[6] = (short)f2bf(v1.z); r[7] = (short)f2bf(v1.w);
    return r;
}

__device__ __forceinline__ unsigned long long pack4(float a, float b, float c, float d) {
    unsigned lo = (unsigned)f2bf(a) | ((unsigned)f2bf(b) << 16);
    unsigned hi = (unsigned)f2bf(c) | ((unsigned)f2bf(d) << 16);
    return (unsigned long long)lo | ((unsigned long long)hi << 32);
}

// Coalesced publish: lane (m16=local col, hi=row quad) stores one u64 at
// slot + (col*4 + q)*8, packing rows 4q..4q+3 of its column.
__device__ __forceinline__ void pub512(char* slot, int m16, int hi, const float* v) {
    __hip_atomic_store((unsigned long long*)(slot + (m16 * 4 + hi) * 8),
                       pack4(v[0], v[1], v[2], v[3]),
                       __ATOMIC_RELAXED, __HIP_MEMORY_SCOPE_AGENT);
}

// ---------------- main recurrent kernel ----------------
// grid: 128 blocks = 16 rowgroups x 8 colgroups. 256 threads = 4 waves:
// wave w: tile tt = 2*cg + (w>>1), role (w&1): 0 = h-path, 1 = z-path.
// ALL weights for the wave's tile+role live in registers (loaded once).
// Exchange: coalesced u64 publish to per-tile slots; counter barrier;
// pair-unpack readback into swizzled LDS.
__launch_bounds__(256, 1)
__global__ void twistor_main(const float* __restrict__ x, unsigned short* __restrict__ ws,
                             float* __restrict__ y) {
    __shared__ unsigned short sst[4][4096];   // h, zr, zi, za [16 x 256 bf16], swizzled
    __shared__ float yslot[2][64][4];         // OZ partial from z-wave -> h-wave (per tile)

    const int tid  = threadIdx.x;
    const int lane = tid & 63;
    const int w    = tid >> 6;          // 0..3
    const int half = w >> 1;            // tile within block: 0/1
    const int role = w & 1;             // 0 = h-wave, 1 = z-wave
    const int m16  = lane & 15;
    const int hi   = lane >> 4;
    const int loff = lane * 8;
    const int bid  = blockIdx.x;
    const int rg   = bid >> 3;          // rowgroup 0..15
    const int cg   = bid & 7;           // colgroup 0..7
    const int tt   = cg * 2 + half;     // this wave's col tile 0..15
    const int brow0 = rg * 16;
    const int n    = tt * 16 + m16;
    const float* bias = (const float*)((const char*)ws + BIAS_OFF_BYTES);
    unsigned* ctr = (unsigned*)((char*)ws + CTR_OFF_BYTES) + rg * 16;
    char* simg = (char*)ws + STATE_OFF_BYTES;

    // zero ALL state LDS (t=0 state is all zeros) -- 4096 u64 = full 32KB.
    // CRITICAL: stale LDS can decode as bf16 NaN -> permanent NaN (round-7 lesson).
    for (int i = tid; i < 4096; i += 256) ((unsigned long long*)sst)[i] = 0;
    __syncthreads();

    // ---- per-wave weight registers ----
    bf16x8 wA[8], wB[8], wC[8], wU[4], wO[8];   // role-dependent meaning
    if (role == 0) {
        wload<8>(wA, ws + G_WH    * 65536 + tt * 4096, loff);   // WH
        wload<8>(wB, ws + G_WTAUH * 65536 + tt * 4096, loff);   // WTAUH
        wload<8>(wC, ws + G_Z2H   * 65536 + tt * 4096, loff);   // Z2H*CPL
        wload<4>(wU, ws + UH + tt * 2048, loff);                // UH
        if (tt < 4) wload<8>(wO, ws + OH + tt * 4096, loff);    // OH
    } else {
        wload<8>(wA, ws + G_WZR   * 65536 + tt * 4096, loff);   // WZR
        wload<8>(wB, ws + G_WZI   * 65536 + tt * 4096, loff);   // WZI
        wload<8>(wC, ws + G_H2Z   * 65536 + tt * 4096, loff);   // H2Z*CPL
        wload<4>(wU, ws + UZ + tt * 2048, loff);                // UZ
        if (tt < 4) wload<8>(wO, ws + OZ + tt * 4096, loff);    // OZ
    }
    bf16x8 wTZ[8];
    if (role == 1) wload<8>(wTZ, ws + G_WTAUZ * 65536 + tt * 4096, loff);

    const float bthh = bias[BT_H + n],    btauh = bias[BTAU_H + n], bht = bias[BH_TOT + n];
    const float btzr = bias[BT_ZR + n],   btzi  = bias[BT_ZI + n],  btauz = bias[BTAU_Z + n];
    const float bzrt = bias[BZR_TOT + n], bzit  = bias[BZI_TOT + n];
    const float by_  = (tt < 4 && role == 0) ? bias[BY + n] : 0.f;

    float s0_[4] = {0, 0, 0, 0};   // role 0: h ; role 1: zr
    float s1_[4] = {0, 0, 0, 0};   // role 1: zi (unused for role 0)

    bf16x8 ax[4];
    {
        const float* xrow = x + ((size_t)brow0 + m16) * INP_;
#pragma unroll
        for (int kt = 0; kt < 4; ++kt) ax[kt] = loadXfrag(xrow, kt * 32 + hi * 8);
    }

    for (int t = 0; t < T_; ++t) {
        const int p = (t + 1) & 1;
        char* img  = simg + (size_t)(p * 16 + rg) * 32768;
        char* slot = img + tt * 2048;          // this tile's 2KB

        bf16x8 ah[8], azr[8];
        loadA8(sst[0], m16, hi, ah);
        loadA8(sst[1], m16, hi, azr);

        f32x4 a_y = {0.f, 0.f, 0.f, 0.f};
        if (tt < 4 && t > 0) {
            if (role == 0) {
                wgemm<8>(ah, wO, a_y);
            } else {
                wgemm<8>(azr, wO, a_y);
                *(f32x4*)yslot[half][lane] = a_y;
            }
        }

        if (role == 0) {
            // ---- h-path ----
            f32x4 a_th = {0.f, 0.f, 0.f, 0.f}, a_tau = {0.f, 0.f, 0.f, 0.f};
            f32x4 a_ch = {0.f, 0.f, 0.f, 0.f};
            wgemm<8>(ah,  wA, a_th);
            wgemm<8>(ah,  wB, a_tau);
            wgemm<8>(azr, wC, a_ch);
            wgemm<4>(ax,  wU, a_ch);
            float hn[4];
#pragma unroll
            for (int j = 0; j < 4; ++j) {
                float th = fminf(fmaxf(sigmoid_fast(a_tau[j] + btauh), 0.01f), 1.0f) + 1e-6f;
                float dh = -s0_[j] + tanh_fast(a_th[j] + bthh) + a_ch[j] + bht;
                hn[j]    = s0_[j] + DT_ * dh * rcp_(th);
                s0_[j] = hn[j];
            }
            pub512(slot, m16, hi, hn);                       // state 0 (h)
        } else {
            // ---- z-path ----
            f32x4 a_tzr = {0.f, 0.f, 0.f, 0.f}, a_tzi = {0.f, 0.f, 0.f, 0.f};
            f32x4 a_tz  = {0.f, 0.f, 0.f, 0.f}, a_cz  = {0.f, 0.f, 0.f, 0.f};
            wgemm<8>(azr, wA, a_tzr);
            wgemm<8>(ah,  wC, a_cz);
            {
                bf16x8 azi[8];
                loadA8(sst[2], m16, hi, azi);
                wgemm<8>(azi, wB, a_tzi);
            }
            {
                bf16x8 aza[8];
                loadA8(sst[3], m16, hi, aza);
                wgemm<8>(aza, wTZ, a_tz);
            }
            wgemm<4>(ax, wU, a_cz);
            float zrn[4], zin[4], zan[4];
#pragma unroll
            for (int j = 0; j < 4; ++j) {
                float tz  = fminf(fmaxf(sigmoid_fast(a_tz[j] + btauz), 0.01f), 1.0f) + 1e-6f;
                float rtz = rcp_(tz);
                float dzr = -s0_[j] + tanh_fast(a_tzr[j] + btzr) + a_cz[j] + bzrt;
                float dzi = -s1_[j] + tanh_fast(a_tzi[j] + btzi) + a_cz[j] + bzit;
                zrn[j] = s0_[j] + DT_ * dzr * rtz;
                zin[j] = s1_[j] + DT_ * dzi * rtz;
                zan[j] = sqrtf(zrn[j] * zrn[j] + zin[j] * zin[j] + 1e-24f);
                s0_[j] = zrn[j]; s1_[j] = zin[j];
            }
            pub512(slot + 512,  m16, hi, zrn);               // state 1 (zr)
            pub512(slot + 1024, m16, hi, zin);               // state 2 (zi)
            pub512(slot + 1536, m16, hi, zan);               // state 3 (za)
        }
        __syncthreads();   // (1) LDS reads done; publish stores drained; yslot ready

        // ---- overlap window: y store, x prefetch, counter arrive+wait ----
        if (tt < 4 && role == 0 && t > 0) {
            f32x4 yz = *(const f32x4*)yslot[half][lane];
#pragma unroll
            for (int j = 0; j < 4; ++j)
                y[((size_t)(t - 1) * B_ + brow0 + hi * 4 + j) * OUT_ + n] =
                    a_y[j] + yz[j] + by_;
        }
        if (t + 1 < T_) {
            const float* xrow = x + ((size_t)(t + 1) * B_ + brow0 + m16) * INP_;
#pragma unroll
            for (int kt = 0; kt < 4; ++kt) ax[kt] = loadXfrag(xrow, kt * 32 + hi * 8);
        }
        if (tid == 255) {
            __hip_atomic_fetch_add(ctr, 1u, __ATOMIC_RELAXED, __HIP_MEMORY_SCOPE_AGENT);
            const unsigned tgt = 8u * (unsigned)(t + 1);
            while (__hip_atomic_load(ctr, __ATOMIC_RELAXED, __HIP_MEMORY_SCOPE_AGENT) < tgt)
                __builtin_amdgcn_s_sleep(2);
        }
        __syncthreads();   // (2) all 8 peers published

        // ---- pair-unpack read-back: [tile][state][col*4+q] u64s -> swizzled sst ----
        {
            const unsigned long long* img8 = (const unsigned long long*)img;
#pragma unroll
            for (int c = 0; c < 8; ++c) {
                const int pi   = tid + 256 * c;
                const int tile = pi >> 7;
                const int rem  = pi & 127;
                const int s    = rem >> 5;
                const int rem2 = rem & 31;
                const int cp   = rem2 >> 2;      // col pair (local cols 2cp, 2cp+1)
                const int q    = rem2 & 3;       // row quad
                const int b0   = tile * 256 + s * 64 + cp * 8 + q;
                unsigned long long A = __hip_atomic_load(img8 + b0, __ATOMIC_RELAXED,
                                                         __HIP_MEMORY_SCOPE_AGENT);
                unsigned long long Bv = __hip_atomic_load(img8 + b0 + 4, __ATOMIC_RELAXED,
                                                          __HIP_MEMORY_SCOPE_AGENT);
                char* sb_ = (char*)sst[s];
                const int ncb = (tile * 16 + cp * 2) * 2;   // byte col offset
#pragma unroll
                for (int e = 0; e < 4; ++e) {
                    const int r = q * 4 + e;
                    unsigned u = (unsigned)((A >> (16 * e)) & 0xffffu) |
                                 ((unsigned)((Bv >> (16 * e)) & 0xffffu) << 16);
                    *(unsigned*)(sb_ + ((r * 512 + ncb) ^ ((r & 7) << 4))) = u;
                }
            }
        }
        __syncthreads();   // (3) sst ready for next step
    }

    // final y_{T-1} from S_T (staged in sst by last exchange)
    {
        f32x4 a_y = {0.f, 0.f, 0.f, 0.f};
        if (tt < 4) {
            if (role == 0) {
                bf16x8 ah[8];
                loadA8(sst[0], m16, hi, ah);
                wgemm<8>(ah, wO, a_y);
            } else {
                bf16x8 azr[8];
                loadA8(sst[1], m16, hi, azr);
                wgemm<8>(azr, wO, a_y);
                *(f32x4*)yslot[half][lane] = a_y;
            }
        }
        __syncthreads();
        if (tt < 4 && role == 0) {
            f32x4 yz = *(const f32x4*)yslot[half][lane];
#pragma unroll
            for (int j = 0; j < 4; ++j)
                y[((size_t)(T_ - 1) * B_ + brow0 + hi * 4 + j) * OUT_ + n] =
                    a_y[j] + yz[j] + by_;
        }
    }
}

extern "C" void kernel_launch(void* const* d_in, const int* in_sizes, int n_in,
                              void* d_out, int out_size, void* d_ws, size_t ws_size,
                              hipStream_t stream) {
    const float* x = (const float*)d_in[0];
    unsigned short* ws = (unsigned short*)d_ws;
    float* bias = (float*)((char*)d_ws + BIAS_OFF_BYTES);

    prep_weights<<<(NW_TOTAL / 8 + 255) / 256, 256, 0, stream>>>(
        (const float*)d_in[1],  /* W_h_w */
        (const float*)d_in[5],  /* W_tau_h_w */
        (const float*)d_in[8],  /* W_z_real_w */
        (const float*)d_in[10], /* W_z_imag_w */
        (const float*)d_in[14], /* W_tau_z_w */
        (const float*)d_in[18], /* h2z_w */
        (const float*)d_in[20], /* z2h_w */
        (const float*)d_in[3],  /* U_h_w */
        (const float*)d_in[12], /* U_z_w */
        (const float*)d_in[22], /* out_h_w */
        (const float*)d_in[24], /* out_z_w */
        ws);
    prep_bias<<<1, 256, 0, stream>>>(
        (const float*)d_in[2],  /* W_h_b */
        (const float*)d_in[6],  /* W_tau_h_b */
        (const float*)d_in[4],  /* U_h_b */
        (const float*)d_in[7],  /* b_h */
        (const float*)d_in[21], /* z2h_b */
        (const float*)d_in[9],  /* W_z_real_b */
        (const float*)d_in[11], /* W_z_imag_b */
        (const float*)d_in[15], /* W_tau_z_b */
        (const float*)d_in[13], /* U_z_b */
        (const float*)d_in[16], /* b_z_real */
        (const float*)d_in[17], /* b_z_imag */
        (const float*)d_in[19], /* h2z_b */
        (const float*)d_in[23], /* out_h_b */
        (const float*)d_in[25], /* out_z_b */
        bias);
    twistor_main<<<128, 256, 0, stream>>>(x, ws, (float*)d_out);
}

// Round 11
// 2866.937 us; speedup vs baseline: 2.0181x; 1.1140x over previous
//
#include <hip/hip_runtime.h>
#include <hip/hip_bf16.h>
#include <math.h>

// ---------------- problem constants ----------------
#define T_    512
#define B_    256
#define INP_  128
#define HID_  256
#define OUT_  64
#define DT_   0.1f
#define CPL_  0.1f

typedef __attribute__((ext_vector_type(8))) short          bf16x8;
typedef __attribute__((ext_vector_type(4))) float          f32x4;
typedef __attribute__((ext_vector_type(4))) unsigned short u16x4;

// ---------------- ws layout (ushort units, FRAGMENT-PERMUTED weights) ----------------
#define G_WH    0
#define G_WTAUH 1
#define G_WZR   2
#define G_WZI   3
#define G_WTAUZ 4
#define G_H2Z   5
#define G_Z2H   6
#define UH     458752   // 7*65536
#define UZ     491520
#define OH     524288
#define OZ     540672
#define NW_TOTAL 557056
#define BIAS_OFF_BYTES (NW_TOTAL * 2)
#define BT_H    0
#define BTAU_H  256
#define BH_TOT  512
#define BT_ZR   768
#define BT_ZI   1024
#define BTAU_Z  1280
#define BZR_TOT 1536
#define BZI_TOT 1792
#define BY      2048   // 64 floats
#define FLAGS_OFF_BYTES (BIAS_OFF_BYTES + 8448)   // 16 rg x 8 cg x 64B = 8 KB
#define STATE_OFF_BYTES (FLAGS_OFF_BYTES + 8192)
// state image (ROW-MAJOR fragment-friendly):
// [parity2][rg16] of { [state4][tile16][row16][col16] bf16 } = 32 KB per (parity,rg).
// Publishers scatter paired-u32 agent stores (r6/r8/r9-proven pairing) into their
// tile's dense 512B slice; readers load 16B A-fragments directly as u64 pairs.

// fp32 -> bf16, round-to-nearest-even
__device__ __forceinline__ unsigned short f2bf(float f) {
    unsigned int u = __float_as_uint(f);
    u += 0x7fffu + ((u >> 16) & 1u);
    return (unsigned short)(u >> 16);
}

__device__ __forceinline__ float rcp_(float x) { return __builtin_amdgcn_rcpf(x); }
__device__ __forceinline__ float sigmoid_fast(float x) {
    return rcp_(1.0f + __expf(-x));
}
__device__ __forceinline__ float tanh_fast(float x) {
    return 1.0f - 2.0f * rcp_(__expf(2.0f * x) + 1.0f);
}

// ---------------- prep: weights fp32 -> bf16, fragment-permuted ----------------
__global__ void prep_weights(const float* __restrict__ Wh,   const float* __restrict__ Wtauh,
                             const float* __restrict__ Wzr,  const float* __restrict__ Wzi,
                             const float* __restrict__ Wtauz,const float* __restrict__ h2z,
                             const float* __restrict__ z2h,  const float* __restrict__ Uh,
                             const float* __restrict__ Uz,   const float* __restrict__ oh,
                             const float* __restrict__ oz,   unsigned short* __restrict__ ws) {
    int fid = blockIdx.x * 256 + threadIdx.x;   // one 8-elem fragment per thread
    if (fid >= NW_TOTAL / 8) return;
    int o = fid * 8;
    const float* src;
    int row, col, K;
    float scale = 1.0f;
    if (o < UH) {                       // H region, K=256
        int g  = o >> 16;
        int r  = o & 65535;
        int T  = r >> 12;
        int r2 = r & 4095;
        int kt = r2 >> 9;
        int l  = (r2 & 511) >> 3;
        row = T * 16 + (l & 15);
        col = kt * 32 + (l >> 4) * 8;
        K = 256;
        if      (g == G_WH)    src = Wh;
        else if (g == G_WTAUH) src = Wtauh;
        else if (g == G_WZR)   src = Wzr;
        else if (g == G_WZI)   src = Wzi;
        else if (g == G_WTAUZ) src = Wtauz;
        else if (g == G_H2Z)   { src = h2z; scale = CPL_; }
        else                   { src = z2h; scale = CPL_; }
    } else if (o < OH) {                // U region, K=128
        int g  = (o - UH) >> 15;
        int r  = (o - UH) & 32767;
        int T  = r >> 11;
        int r2 = r & 2047;
        int kt = r2 >> 9;
        int l  = (r2 & 511) >> 3;
        row = T * 16 + (l & 15);
        col = kt * 32 + (l >> 4) * 8;
        K = 128;
        src = g ? Uz : Uh;
    } else {                            // OUT region, K=256
        int g  = (o - OH) >> 14;
        int r  = (o - OH) & 16383;
        int T  = r >> 12;
        int r2 = r & 4095;
        int kt = r2 >> 9;
        int l  = (r2 & 511) >> 3;
        row = T * 16 + (l & 15);
        col = kt * 32 + (l >> 4) * 8;
        K = 256;
        src = g ? oz : oh;
    }
    const float* p = src + (size_t)row * K + col;
    float4 v0 = *(const float4*)p;
    float4 v1 = *(const float4*)(p + 4);
    u16x4 a, b;
    a.x = f2bf(v0.x * scale); a.y = f2bf(v0.y * scale);
    a.z = f2bf(v0.z * scale); a.w = f2bf(v0.w * scale);
    b.x = f2bf(v1.x * scale); b.y = f2bf(v1.y * scale);
    b.z = f2bf(v1.z * scale); b.w = f2bf(v1.w * scale);
    *(u16x4*)(ws + o)     = a;
    *(u16x4*)(ws + o + 4) = b;
}

// ---------------- prep: folded biases (fp32) ----------------
__global__ void prep_bias(const float* __restrict__ Whb,  const float* __restrict__ Wtauhb,
                          const float* __restrict__ Uhb,  const float* __restrict__ bh,
                          const float* __restrict__ z2hb, const float* __restrict__ Wzrb,
                          const float* __restrict__ Wzib, const float* __restrict__ Wtauzb,
                          const float* __restrict__ Uzb,  const float* __restrict__ bzr,
                          const float* __restrict__ bzi,  const float* __restrict__ h2zb,
                          const float* __restrict__ ohb,  const float* __restrict__ ozb,
                          float* __restrict__ bias) {
    int n = threadIdx.x;
    if (n < 256) {
        bias[BT_H + n]    = Whb[n];
        bias[BTAU_H + n]  = Wtauhb[n];
        bias[BH_TOT + n]  = Uhb[n] + bh[n] + CPL_ * z2hb[n];
        bias[BT_ZR + n]   = Wzrb[n];
        bias[BT_ZI + n]   = Wzib[n];
        bias[BTAU_Z + n]  = Wtauzb[n];
        bias[BZR_TOT + n] = Uzb[n] + bzr[n] + CPL_ * h2zb[n];
        bias[BZI_TOT + n] = Uzb[n] + bzi[n] + CPL_ * h2zb[n];
        if (n < 64) bias[BY + n] = ohb[n] + ozb[n];
    }
}

// ---------------- prep: zero flags (8KB) + parity-0 state image (512KB) ----------------
// MUST run every launch (graph replay): S_0 = 0 and flags restart at 0.
__global__ void prep_zero(unsigned long long* __restrict__ p) {
    int i = blockIdx.x * 512 + threadIdx.x;
    if (i < 66560) p[i] = 0;    // (8192 + 524288) / 8
}

// Load weight fragments (fragment-permuted ws) into registers, once.
template<int NKT>
__device__ __forceinline__ void wload(bf16x8* w, const unsigned short* __restrict__ p, int loff) {
#pragma unroll
    for (int kt = 0; kt < NKT; ++kt) w[kt] = *(const bf16x8*)(p + kt * 512 + loff);
}

// GEMM with both operands in registers.
template<int NKT>
__device__ __forceinline__ void wgemm(const bf16x8* a, const bf16x8* w, f32x4& acc) {
#pragma unroll
    for (int kt = 0; kt < NKT; ++kt)
        acc = __builtin_amdgcn_mfma_f32_16x16x32_bf16(a[kt], w[kt], acc, 0, 0, 0);
}

// x A-fragment straight from global fp32
__device__ __forceinline__ bf16x8 loadXfrag(const float* __restrict__ xrow, int off) {
    float4 v0 = *(const float4*)(xrow + off);
    float4 v1 = *(const float4*)(xrow + off + 4);
    bf16x8 r;
    r[0] = (short)f2bf(v0.x); r[1] = (short)f2bf(v0.y);
    r[2] = (short)f2bf(v0.z); r[3] = (short)f2bf(v0.w);
    r[4] = (short)f2bf(v1.x); r[5] = (short)f2bf(v1.y);
    r[6] = (short)f2bf(v1.z); r[7] = (short)f2bf(v1.w);
    return r;
}

// Load 8 A-fragments (K=256) for one state DIRECTLY from the row-major image.
// st = image base of this state ([tile16][row16][col16] bf16).
// lane (m16,hi), kt: row m16, global cols kt*32+hi*8 .. +8
//  -> tile 2kt+(hi>>1), byte = tile*512 + m16*32 + (hi&1)*16.
__device__ __forceinline__ void loadAimg(const char* st, int m16, int hi, bf16x8* a) {
    const unsigned long long* b = (const unsigned long long*)
        (st + ((hi >> 1) * 512 + m16 * 32 + (hi & 1) * 16));
#pragma unroll
    for (int kt = 0; kt < 8; ++kt) {
        union { unsigned long long q[2]; bf16x8 v; } u;
        u.q[0] = __hip_atomic_load(b + kt * 128,     __ATOMIC_RELAXED,
                                   __HIP_MEMORY_SCOPE_AGENT);
        u.q[1] = __hip_atomic_load(b + kt * 128 + 1, __ATOMIC_RELAXED,
                                   __HIP_MEMORY_SCOPE_AGENT);
        a[kt] = u.v;
    }
}

// DIRECT row-major publish (no LDS): lane (col m16, rows 4hi..4hi+3) pairs with
// lane m16^1 via shfl (r6/r8/r9-proven pairing) and scatters 2 u32 agent stores:
// rows hi*4 + odd*2 + {0,1}, col-pair (m16&~1). Covers the full 16x16 tile slice.
__device__ __forceinline__ void pub_rm(char* gslot, int m16, int hi, const float* v) {
    const int odd = m16 & 1;
    float oth[4];
#pragma unroll
    for (int j = 0; j < 4; ++j) oth[j] = __shfl_xor(v[j], 1);
#pragma unroll
    for (int k = 0; k < 2; ++k) {
        const int j = odd * 2 + k;
        const int r = hi * 4 + j;
        unsigned a = f2bf(v[j]), b = f2bf(oth[j]);
        unsigned u = odd ? (b | (a << 16)) : (a | (b << 16));
        __hip_atomic_store((unsigned*)(gslot + r * 32 + (m16 & ~1) * 2), u,
                           __ATOMIC_RELAXED, __HIP_MEMORY_SCOPE_AGENT);
    }
}

// Per-wave flag wait: lanes 0..7 poll the 8 peer flags (64B-padded) until all >= tgt.
__device__ __forceinline__ void waitflags(const unsigned* flg, int lane, unsigned tgt) {
    for (;;) {
        unsigned v = tgt;
        if (lane < 8)
            v = __hip_atomic_load(flg + lane * 16, __ATOMIC_RELAXED,
                                  __HIP_MEMORY_SCOPE_AGENT);
        if (__all((int)(v >= tgt))) break;
        __builtin_amdgcn_s_sleep(1);
    }
}

// ---------------- main recurrent kernel ----------------
// grid: 128 blocks; rg = bid&15 (XCD-local peers), cg = bid>>4. 256 threads = 4 waves:
// wave w: tile tt = 2*cg + (w>>1), role (w&1): 0 = h-path (+ full y duty), 1 = z-path.
// Weights in VGPRs; A-fragments loaded DIRECTLY from the row-major global image;
// direct scatter publish (no LDS anywhere); one __syncthreads per step; flag sync.
__launch_bounds__(256, 1)
__global__ void twistor_main(const float* __restrict__ x, unsigned short* __restrict__ ws,
                             float* __restrict__ y) {
    const int tid  = threadIdx.x;
    const int lane = tid & 63;
    const int w    = tid >> 6;          // 0..3
    const int half = w >> 1;            // tile within block: 0/1
    const int role = w & 1;             // 0 = h-wave, 1 = z-wave
    const int m16  = lane & 15;
    const int hi   = lane >> 4;
    const int loff = lane * 8;
    const int bid  = blockIdx.x;
    const int rg   = bid & 15;          // rowgroup 0..15  (peers share XCD)
    const int cg   = bid >> 4;          // colgroup 0..7
    const int tt   = cg * 2 + half;     // this wave's col tile 0..15
    const int brow0 = rg * 16;
    const int n    = tt * 16 + m16;
    const float* bias = (const float*)((const char*)ws + BIAS_OFF_BYTES);
    unsigned* flg    = (unsigned*)((char*)ws + FLAGS_OFF_BYTES) + rg * 128;
    unsigned* myflag = flg + cg * 16;
    char* simg = (char*)ws + STATE_OFF_BYTES;

    // ---- per-wave weight registers ----
    bf16x8 wA[8], wB[8], wC[8], wU[4];
    bf16x8 wO[8], wO2[8];               // role 0 duty: OH, OZ
    bf16x8 wTZ[8];                      // role 1: WTAUZ
    if (role == 0) {
        wload<8>(wA, ws + G_WH    * 65536 + tt * 4096, loff);
        wload<8>(wB, ws + G_WTAUH * 65536 + tt * 4096, loff);
        wload<8>(wC, ws + G_Z2H   * 65536 + tt * 4096, loff);
        wload<4>(wU, ws + UH + tt * 2048, loff);
        if (tt < 4) {
            wload<8>(wO,  ws + OH + tt * 4096, loff);
            wload<8>(wO2, ws + OZ + tt * 4096, loff);
        }
    } else {
        wload<8>(wA, ws + G_WZR   * 65536 + tt * 4096, loff);
        wload<8>(wB, ws + G_WZI   * 65536 + tt * 4096, loff);
        wload<8>(wC, ws + G_H2Z   * 65536 + tt * 4096, loff);
        wload<4>(wU, ws + UZ + tt * 2048, loff);
        wload<8>(wTZ, ws + G_WTAUZ * 65536 + tt * 4096, loff);
    }

    const float bthh = bias[BT_H + n],    btauh = bias[BTAU_H + n], bht = bias[BH_TOT + n];
    const float btzr = bias[BT_ZR + n],   btzi  = bias[BT_ZI + n],  btauz = bias[BTAU_Z + n];
    const float bzrt = bias[BZR_TOT + n], bzit  = bias[BZI_TOT + n];
    const float by_  = (tt < 4 && role == 0) ? bias[BY + n] : 0.f;

    float s0_[4] = {0, 0, 0, 0};   // role 0: h ; role 1: zr
    float s1_[4] = {0, 0, 0, 0};   // role 1: zi

    for (int t = 0; t < T_; ++t) {
        // x fragments (flag-independent -> issue before spin, latency hidden)
        bf16x8 ax[4];
        {
            const float* xrow = x + ((size_t)t * B_ + brow0 + m16) * INP_;
#pragma unroll
            for (int kt = 0; kt < 4; ++kt) ax[kt] = loadXfrag(xrow, kt * 32 + hi * 8);
        }
        if (t > 0) waitflags(flg, lane, (unsigned)t);   // S_t published by all peers

        const char* imgR = simg + (size_t)((t & 1) * 16 + rg) * 32768;
        char*       imgW = simg + (size_t)(((t + 1) & 1) * 16 + rg) * 32768;

        bf16x8 ah[8], azr[8];
        loadAimg(imgR,        m16, hi, ah);
        loadAimg(imgR + 8192, m16, hi, azr);

        if (role == 0) {
            // ---- h-path (+ y duty) ----
            const bool ydo = (tt < 4) && (t > 0);
            f32x4 a_y = {0.f, 0.f, 0.f, 0.f};
            if (ydo) { wgemm<8>(ah, wO, a_y); wgemm<8>(azr, wO2, a_y); }
            f32x4 a_th = {0.f, 0.f, 0.f, 0.f}, a_tau = {0.f, 0.f, 0.f, 0.f};
            f32x4 a_ch = {0.f, 0.f, 0.f, 0.f};
            wgemm<8>(ah,  wA, a_th);
            wgemm<8>(ah,  wB, a_tau);
            wgemm<8>(azr, wC, a_ch);
            wgemm<4>(ax,  wU, a_ch);
            if (ydo) {
#pragma unroll
                for (int j = 0; j < 4; ++j)
                    y[((size_t)(t - 1) * B_ + brow0 + hi * 4 + j) * OUT_ + n] =
                        a_y[j] + by_;
            }
            float hn[4];
#pragma unroll
            for (int j = 0; j < 4; ++j) {
                float th = fminf(fmaxf(sigmoid_fast(a_tau[j] + btauh), 0.01f), 1.0f) + 1e-6f;
                float dh = -s0_[j] + tanh_fast(a_th[j] + bthh) + a_ch[j] + bht;
                hn[j]    = s0_[j] + DT_ * dh * rcp_(th);
                s0_[j] = hn[j];
            }
            pub_rm(imgW + tt * 512, m16, hi, hn);                        // state 0 (h)
        } else {
            // ---- z-path ----
            bf16x8 azi[8], aza[8];
            loadAimg(imgR + 16384, m16, hi, azi);
            loadAimg(imgR + 24576, m16, hi, aza);
            f32x4 a_tzr = {0.f, 0.f, 0.f, 0.f}, a_tzi = {0.f, 0.f, 0.f, 0.f};
            f32x4 a_tz  = {0.f, 0.f, 0.f, 0.f}, a_cz  = {0.f, 0.f, 0.f, 0.f};
            wgemm<8>(azr, wA,  a_tzr);
            wgemm<8>(ah,  wC,  a_cz);
            wgemm<8>(azi, wB,  a_tzi);
            wgemm<8>(aza, wTZ, a_tz);
            wgemm<4>(ax,  wU,  a_cz);
            float zrn[4], zin[4], zan[4];
#pragma unroll
            for (int j = 0; j < 4; ++j) {
                float tz  = fminf(fmaxf(sigmoid_fast(a_tz[j] + btauz), 0.01f), 1.0f) + 1e-6f;
                float rtz = rcp_(tz);
                float dzr = -s0_[j] + tanh_fast(a_tzr[j] + btzr) + a_cz[j] + bzrt;
                float dzi = -s1_[j] + tanh_fast(a_tzi[j] + btzi) + a_cz[j] + bzit;
                zrn[j] = s0_[j] + DT_ * dzr * rtz;
                zin[j] = s1_[j] + DT_ * dzi * rtz;
                zan[j] = sqrtf(zrn[j] * zrn[j] + zin[j] * zin[j] + 1e-24f);
                s0_[j] = zrn[j]; s1_[j] = zin[j];
            }
            pub_rm(imgW + 8192  + tt * 512, m16, hi, zrn);               // state 1 (zr)
            pub_rm(imgW + 16384 + tt * 512, m16, hi, zin);               // state 2 (zi)
            pub_rm(imgW + 24576 + tt * 512, m16, hi, zan);               // state 3 (za)
        }
        __syncthreads();   // all 4 waves' publish stores drained (vmcnt 0 per wave)
        if (tid == 0)
            __hip_atomic_store(myflag, (unsigned)(t + 1), __ATOMIC_RELAXED,
                               __HIP_MEMORY_SCOPE_AGENT);
    }

    // final y_{T-1} from S_T (parity 0)
    if (role == 0 && tt < 4) {
        waitflags(flg, lane, (unsigned)T_);
        const char* imgR = simg + (size_t)((T_ & 1) * 16 + rg) * 32768;
        bf16x8 ah[8], azr[8];
        loadAimg(imgR,        m16, hi, ah);
        loadAimg(imgR + 8192, m16, hi, azr);
        f32x4 a_y = {0.f, 0.f, 0.f, 0.f};
        wgemm<8>(ah,  wO,  a_y);
        wgemm<8>(azr, wO2, a_y);
#pragma unroll
        for (int j = 0; j < 4; ++j)
            y[((size_t)(T_ - 1) * B_ + brow0 + hi * 4 + j) * OUT_ + n] = a_y[j] + by_;
    }
}

extern "C" void kernel_launch(void* const* d_in, const int* in_sizes, int n_in,
                              void* d_out, int out_size, void* d_ws, size_t ws_size,
                              hipStream_t stream) {
    const float* x = (const float*)d_in[0];
    unsigned short* ws = (unsigned short*)d_ws;
    float* bias = (float*)((char*)d_ws + BIAS_OFF_BYTES);

    prep_weights<<<(NW_TOTAL / 8 + 255) / 256, 256, 0, stream>>>(
        (const float*)d_in[1],  /* W_h_w */
        (const float*)d_in[5],  /* W_tau_h_w */
        (const float*)d_in[8],  /* W_z_real_w */
        (const float*)d_in[10], /* W_z_imag_w */
        (const float*)d_in[14], /* W_tau_z_w */
        (const float*)d_in[18], /* h2z_w */
        (const float*)d_in[20], /* z2h_w */
        (const float*)d_in[3],  /* U_h_w */
        (const float*)d_in[12], /* U_z_w */
        (const float*)d_in[22], /* out_h_w */
        (const float*)d_in[24], /* out_z_w */
        ws);
    prep_bias<<<1, 256, 0, stream>>>(
        (const float*)d_in[2],  /* W_h_b */
        (const float*)d_in[6],  /* W_tau_h_b */
        (const float*)d_in[4],  /* U_h_b */
        (const float*)d_in[7],  /* b_h */
        (const float*)d_in[21], /* z2h_b */
        (const float*)d_in[9],  /* W_z_real_b */
        (const float*)d_in[11], /* W_z_imag_b */
        (const float*)d_in[15], /* W_tau_z_b */
        (const float*)d_in[13], /* U_z_b */
        (const float*)d_in[16], /* b_z_real */
        (const float*)d_in[17], /* b_z_imag */
        (const float*)d_in[19], /* h2z_b */
        (const float*)d_in[23], /* out_h_b */
        (const float*)d_in[25], /* out_z_b */
        bias);
    prep_zero<<<130, 512, 0, stream>>>(
        (unsigned long long*)((char*)d_ws + FLAGS_OFF_BYTES));
    twistor_main<<<128, 256, 0, stream>>>(x, ws, (float*)d_out);
}